// Round 11
// baseline (22.503 us; speedup 1.0000x reference)
//
#include <hip/hip_runtime.h>
#include <hip/hip_bf16.h>

#define B 8
#define N 4096
#define BN (B * N)            // 32768 nodes
#define NBLK 256              // 8 b x 32 qb (128 queries each)

typedef __attribute__((ext_vector_type(16))) float f32x16;
typedef __attribute__((ext_vector_type(8)))  short bf16x8;

__device__ __forceinline__ float min3f(float a, float b, float c) {
    float d;
    asm("v_min3_f32 %0, %1, %2, %3" : "=v"(d) : "v"(a), "v"(b), "v"(c));
    return d;
}
__device__ __forceinline__ unsigned short f2bf(float x) {
    __hip_bfloat16 h = __float2bfloat16(x);
    return *reinterpret_cast<unsigned short*>(&h);
}
__device__ __forceinline__ float bf2f(unsigned short u) {
    __hip_bfloat16 h;
    *reinterpret_cast<unsigned short*>(&h) = u;
    return __bfloat162float(h);
}

// Convert one candidate (x,y,z) to its two A-fragment halves and write to LDS.
// half0 k-slots {Hx,Hy,Hz,Lx,Ly,Lz,Hx,Hy}, half1 {Hz,nh,nl,0...} where
// H=bf16(-2c), L=bf16(-2c-H), nh/nl = bf16-split(|c|^2)  [R8/R9-verified].
__device__ __forceinline__ void stage1(unsigned short* buf, int cl,
                                       float x, float y, float z) {
    float m2x = -2.f * x, m2y = -2.f * y, m2z = -2.f * z;
    unsigned short Hx = f2bf(m2x), Hy = f2bf(m2y), Hz = f2bf(m2z);
    unsigned short Lx = f2bf(m2x - bf2f(Hx));
    unsigned short Ly = f2bf(m2y - bf2f(Hy));
    unsigned short Lz = f2bf(m2z - bf2f(Hz));
    float nc = fmaf(z, z, fmaf(y, y, x * x));
    unsigned short nh = f2bf(nc), nl = f2bf(nc - bf2f(nh));
    int base = ((cl >> 5) << 9) + ((cl & 31) << 3);   // tile*512 + lane*8 shorts
    *(bf16x8*)(buf + base) =
        (bf16x8){(short)Hx, (short)Hy, (short)Hz, (short)Lx,
                 (short)Ly, (short)Lz, (short)Hx, (short)Hy};
    *(bf16x8*)(buf + base + 256) =
        (bf16x8){(short)Hz, (short)nh, (short)nl, 0, 0, 0, 0, 0};
}

// ---------------- k_fused: full NN-min + loss partial, one pass -------------
// Block (256 thr = 4 waves) = 128 queries; wave w owns 32 queries (1 B-frag,
// held in VGPRs). Loop over ALL 4096 candidates in 8 chunks of 512, double-
// buffered LDS (2 x 16 KB), register-prefetch of chunk k+2 during compute of
// chunk k. Per chunk: 16 tiles x (linear ds_read_b128 + mfma_32x32x16_bf16 +
// 8 v_min3). Self-pairs masked on the (wave-uniform) diagonal tile.
// Epilogue: per-query loss, block reduce, ONE plain double store per block.
// A-frag: row=l&31 (cand), k=(l>>5)*8+j. B-frag: col=l&31 (query), same k.
// C/D: col=l&31, row=(reg&3)+8*(reg>>2)+4*(l>>5)  [m74/m101 + R8/R9-verified].
__global__ __launch_bounds__(256) void k_fused(const float* __restrict__ c,
                                               double* __restrict__ partials) {
    __shared__ unsigned short A[2][8192];   // 2 x 16 KB chunk buffers

    int blk = blockIdx.x;
    int qb  = blk & 31;
    int b   = blk >> 5;
    int t   = threadIdx.x;
    int l   = t & 63;
    int w   = __builtin_amdgcn_readfirstlane(t >> 6);

    const float* cb = c + (size_t)b * N * 3;
    int Q0w = (qb << 7) + (w << 5);         // this wave's 32 queries

    // ---- B-frag + |q|^2 (fp32, kept for epilogue) ----
    int qi = Q0w + (l & 31);
    const float* pq = cb + 3 * qi;
    float qx = pq[0], qy = pq[1], qz = pq[2];
    float nq = fmaf(qz, qz, fmaf(qy, qy, qx * qx));
    bf16x8 bfq;
    {
        const short one = (short)0x3F80;    // bf16(1.0)
        if (l < 32) {                       // k-slots 0..7
            unsigned short hx = f2bf(qx), hy = f2bf(qy), hz = f2bf(qz);
            unsigned short lx = f2bf(qx - bf2f(hx));
            unsigned short ly = f2bf(qy - bf2f(hy));
            bfq = (bf16x8){(short)hx, (short)hy, (short)hz, (short)hx,
                           (short)hy, (short)hz, (short)lx, (short)ly};
        } else {                            // k-slots 8..15
            unsigned short hz = f2bf(qz);
            unsigned short lz = f2bf(qz - bf2f(hz));
            bfq = (bf16x8){(short)lz, one, one, 0, 0, 0, 0, 0};
        }
    }

    // self-hit lane math [R8-verified]
    bool sel  = (((l >> 2) & 1) == (l >> 5));
    int  rsel = (l & 3) | (((l & 31) >> 3) << 2);

    // ---- prologue: stage chunk 0, prefetch chunk 1 into regs ----
    {
        const float* p0 = cb + 3 * t;
        const float* p1 = cb + 3 * (256 + t);
        stage1(A[0], t,       p0[0], p0[1], p0[2]);
        stage1(A[0], 256 + t, p1[0], p1[1], p1[2]);
    }
    float ra0, ra1, ra2, rb0, rb1, rb2;
    {
        const float* p0 = cb + 3 * (512 + t);
        const float* p1 = cb + 3 * (512 + 256 + t);
        ra0 = p0[0]; ra1 = p0[1]; ra2 = p0[2];
        rb0 = p1[0]; rb1 = p1[1]; rb2 = p1[2];
    }
    __syncthreads();

    const float INF = __uint_as_float(0x7F800000u);
    float mm[8];
    #pragma unroll
    for (int i = 0; i < 8; ++i) mm[i] = INF;
    f32x16 z16 = {0.f, 0.f, 0.f, 0.f, 0.f, 0.f, 0.f, 0.f,
                  0.f, 0.f, 0.f, 0.f, 0.f, 0.f, 0.f, 0.f};

    for (int k = 0; k < 8; ++k) {
        const unsigned short* buf = A[k & 1];
        // write chunk k+1 into the other buffer; prefetch chunk k+2 to regs
        if (k < 7) {
            unsigned short* nb = A[(k + 1) & 1];
            stage1(nb, t,       ra0, ra1, ra2);
            stage1(nb, 256 + t, rb0, rb1, rb2);
            if (k < 6) {
                int base = (k + 2) << 9;
                const float* p0 = cb + 3 * (base + t);
                const float* p1 = cb + 3 * (base + 256 + t);
                ra0 = p0[0]; ra1 = p0[1]; ra2 = p0[2];
                rb0 = p1[0]; rb1 = p1[1]; rb2 = p1[2];
            }
        }

        int rel = Q0w - (k << 9);
        int dt  = ((unsigned)rel < 512u) ? (rel >> 5) : -1;

        #pragma unroll 4
        for (int tile = 0; tile < 16; ++tile) {
            bf16x8 a = *(const bf16x8*)(buf + (tile << 9) + l * 8);
            f32x16 d = __builtin_amdgcn_mfma_f32_32x32x16_bf16(a, bfq, z16, 0, 0, 0);
            if (tile == dt) {
                #pragma unroll
                for (int i = 0; i < 16; ++i)
                    d[i] = (sel && rsel == i) ? INF : d[i];
            }
            #pragma unroll
            for (int i = 0; i < 8; ++i)
                mm[i] = min3f(mm[i], d[2 * i], d[2 * i + 1]);
        }
        __syncthreads();
    }

    // ---- epilogue: per-query loss, block reduce, one store ----
    float M = min3f(min3f(mm[0], mm[1], mm[2]),
                    min3f(mm[3], mm[4], mm[5]),
                    fminf(mm[6], mm[7]));
    M = fminf(M, __shfl_xor(M, 32));        // combine the two row-halves

    double s = 0.0;
    if (l < 32) {                           // lane l owns query Q0w + l
        float d2 = fmaxf(M + nq, 0.0f);
        float e  = sqrtf(d2) - 0.2f;
        s = (double)(e * e);
    }
    for (int off = 32; off; off >>= 1) s += __shfl_down(s, off);
    __shared__ double sh[4];
    if (l == 0) sh[w] = s;
    __syncthreads();
    if (t == 0) partials[blk] = sh[0] + sh[1] + sh[2] + sh[3];
}

// ---------------- k_sum: fold 256 partials in fixed order -> scalar ---------
__global__ __launch_bounds__(256) void k_sum(const double* __restrict__ partials,
                                             float* __restrict__ out) {
    int t = threadIdx.x;
    double s = partials[t];
    for (int off = 32; off; off >>= 1) s += __shfl_down(s, off);
    __shared__ double sh[4];
    if ((t & 63) == 0) sh[t >> 6] = s;
    __syncthreads();
    if (t == 0) out[0] = (float)((sh[0] + sh[1] + sh[2] + sh[3]) / (double)BN);
}

// ---------------- fallback (tiny workspace): fused single kernel ------------
__global__ __launch_bounds__(64) void k_single(const float* __restrict__ c,
                                               float* __restrict__ out) {
    __shared__ float sx[N], sy[N], sz[N];
    int blk = blockIdx.x;
    int qt  = blk & (N / 64 - 1);
    int b   = blk / (N / 64);
    const float* cb = c + (size_t)b * N * 3;
    int t = threadIdx.x;

    for (int k = t; k < N; k += 64) {
        sx[k] = cb[3 * k];
        sy[k] = cb[3 * k + 1];
        sz[k] = cb[3 * k + 2];
    }
    __syncthreads();

    int   qi = qt * 64 + t;
    float qx = sx[qi], qy = sy[qi], qz = sz[qi];
    const float INF = __uint_as_float(0x7F800000u);
    float m0 = INF, m1 = INF;
    for (int k = 0; k < N; k += 2) {
        float dx0 = qx - sx[k],     dy0 = qy - sy[k],     dz0 = qz - sz[k];
        float dx1 = qx - sx[k + 1], dy1 = qy - sy[k + 1], dz1 = qz - sz[k + 1];
        float d0 = dx0 * dx0 + dy0 * dy0 + dz0 * dz0;
        float d1 = dx1 * dx1 + dy1 * dy1 + dz1 * dz1;
        d0 = (k + 0 == qi) ? INF : d0;
        d1 = (k + 1 == qi) ? INF : d1;
        m0 = fminf(m0, d0);
        m1 = fminf(m1, d1);
    }
    float e = sqrtf(fminf(m0, m1)) - 0.2f;
    float v = e * e;
    for (int off = 32; off; off >>= 1) v += __shfl_down(v, off);
    if (t == 0) atomicAdd(out, v / (float)BN);
}

extern "C" void kernel_launch(void* const* d_in, const int* in_sizes, int n_in,
                              void* d_out, int out_size, void* d_ws, size_t ws_size,
                              hipStream_t stream) {
    const float* c   = (const float*)d_in[0];
    float*       out = (float*)d_out;

    const size_t need = (size_t)NBLK * sizeof(double);    // 2 KB
    if (ws_size >= need) {
        double* partials = (double*)d_ws;
        k_fused<<<NBLK, 256, 0, stream>>>(c, partials);
        k_sum  <<<1, 256, 0, stream>>>(partials, out);
    } else {
        hipMemsetAsync(d_out, 0, sizeof(float), stream);
        k_single<<<B * (N / 64), 64, 0, stream>>>(c, out);
    }
}